// Round 2
// baseline (153.780 us; speedup 1.0000x reference)
//
#include <hip/hip_runtime.h>
#include <hip/hip_bf16.h>
#include <math.h>

// Block-sparse local+strided causal attention, MI355X (gfx950).
// Round 2: prep kernel converts K -> bf16 [h][t][d] and V -> bf16^T [h][d][t]
// into d_ws; attention kernel uses 1-wave workgroups (32 q-rows each), loads
// K/V MFMA fragments DIRECTLY from global bf16 (no LDS staging, no barriers),
// static-max online softmax (no per-iter max/sum butterflies, no O rescale).

#define NHEADS 16
#define HDIM   64
#define BSZ    64
#define NBLK   64
#define SEQLEN 4096
#define KP     72     // P-scratch pitch (shorts): 2-way LDS aliasing only (free)
#define SMAX   16.0f  // static softmax max in exp2 domain (scores*log2e ~ N(0,1.44), |.|<9)

typedef __attribute__((ext_vector_type(8))) short bf16x8;
typedef __attribute__((ext_vector_type(4))) float f32x4;

__device__ __forceinline__ short f2bf(float x) {
    union { float f; unsigned u; } c; c.f = x;
    unsigned u = c.u;
    return (short)((u + 0x7FFFu + ((u >> 16) & 1u)) >> 16); // RNE fp32->bf16
}

// ---------------- prep: fp32 [t][h][d] -> bf16 kh[h][t][d], vth[h][d][t] ----
__global__ __launch_bounds__(256)
void prep_kernel(const float* __restrict__ k, const float* __restrict__ v,
                 short* __restrict__ kh, short* __restrict__ vth) {
    const int b = blockIdx.x, tid = threadIdx.x;
    if (b < NHEADS * NBLK) {            // V^T tiles (64x64 per (h, t-block))
        __shared__ short tile[64 * 65];
        const int h = b & 15, tb = b >> 4;
        #pragma unroll
        for (int it = 0; it < 4; ++it) {
            int e = it * 1024 + tid * 4;
            int t = e >> 6, d = e & 63;
            float4 f = *(const float4*)(v + ((size_t)(tb * 64 + t) * NHEADS + h) * HDIM + d);
            tile[t * 65 + d + 0] = f2bf(f.x);
            tile[t * 65 + d + 1] = f2bf(f.y);
            tile[t * 65 + d + 2] = f2bf(f.z);
            tile[t * 65 + d + 3] = f2bf(f.w);
        }
        __syncthreads();
        #pragma unroll
        for (int it = 0; it < 4; ++it) {
            int e = it * 1024 + tid * 4;
            int d = e >> 6, t = e & 63;
            short4 s4;
            s4.x = tile[(t + 0) * 65 + d];
            s4.y = tile[(t + 1) * 65 + d];
            s4.z = tile[(t + 2) * 65 + d];
            s4.w = tile[(t + 3) * 65 + d];
            *(short4*)(vth + ((size_t)h * HDIM + d) * SEQLEN + tb * 64 + t) = s4;
        }
    } else {                            // K convert (no transpose)
        const int bb = b - NHEADS * NBLK;
        const int h = bb & 15, tb = bb >> 4;
        #pragma unroll
        for (int it = 0; it < 4; ++it) {
            int e = it * 1024 + tid * 4;
            int t = e >> 6, d = e & 63;
            float4 f = *(const float4*)(k + ((size_t)(tb * 64 + t) * NHEADS + h) * HDIM + d);
            short4 s4;
            s4.x = f2bf(f.x); s4.y = f2bf(f.y); s4.z = f2bf(f.z); s4.w = f2bf(f.w);
            *(short4*)(kh + ((size_t)h * SEQLEN + tb * 64 + t) * HDIM + d) = s4;
        }
    }
}

// ---------------- attention: 1 wave per WG, 32 q-rows ----------------------
__global__ __launch_bounds__(64, 4)
void attn_kernel(const short* __restrict__ kh, const short* __restrict__ vth,
                 const float* __restrict__ q, float* __restrict__ out) {
    __shared__ short pl[32 * KP];       // P C->A layout round-trip (wave-private)

    const int b    = blockIdx.x;
    const int h    = b & 15;
    const int idx  = b >> 4;            // 0..127
    const int qi   = idx >> 1;
    const int half = idx & 1;
    const int lane = threadIdx.x;
    const int l16  = lane & 15;
    const int quad = lane >> 4;
    const int row0 = qi * 64 + half * 32;

    // Q A-fragments for 2 stripes (A[m=l16][k=quad*8+j])
    bf16x8 a_q[2][2];
    #pragma unroll
    for (int s = 0; s < 2; ++s) {
        const float* qrow = q + ((size_t)((row0 + s * 16 + l16) * NHEADS + h)) * HDIM;
        #pragma unroll
        for (int kk = 0; kk < 2; ++kk) {
            const float* src = qrow + kk * 32 + quad * 8;
            float4 f0 = *(const float4*)(src);
            float4 f1 = *(const float4*)(src + 4);
            bf16x8 a;
            a[0]=f2bf(f0.x); a[1]=f2bf(f0.y); a[2]=f2bf(f0.z); a[3]=f2bf(f0.w);
            a[4]=f2bf(f1.x); a[5]=f2bf(f1.y); a[6]=f2bf(f1.z); a[7]=f2bf(f1.w);
            a_q[s][kk] = a;
        }
    }

    f32x4 o[2][4];
    float lsum[2][4];
    #pragma unroll
    for (int s = 0; s < 2; ++s)
        #pragma unroll
        for (int nt = 0; nt < 4; ++nt) {
            o[s][nt] = (f32x4){0.f, 0.f, 0.f, 0.f};
            lsum[s][nt] = 0.f;
        }

    const short* kb = kh + (size_t)h * SEQLEN * HDIM;
    const short* vb = vth + (size_t)h * HDIM * SEQLEN;
    const float kscale = 0.125f * 1.4426950408889634f;

    for (int jb = 0; jb <= qi; ++jb) {
        if (!(((qi - jb) < 8) || (((jb + h + 1) & 7) == 0))) continue;

        // ---- S = Q K^T : K B-frags direct from global bf16 [h][t][d] ----
        f32x4 s0[2][4];
        #pragma unroll
        for (int nt = 0; nt < 4; ++nt) {
            s0[0][nt] = (f32x4){0.f, 0.f, 0.f, 0.f};
            s0[1][nt] = (f32x4){0.f, 0.f, 0.f, 0.f};
        }
        #pragma unroll
        for (int nt = 0; nt < 4; ++nt) {
            const short* krow = kb + (size_t)(jb * 64 + nt * 16 + l16) * HDIM + quad * 8;
            bf16x8 k0 = *(const bf16x8*)(krow);
            bf16x8 k1 = *(const bf16x8*)(krow + 32);
            s0[0][nt] = __builtin_amdgcn_mfma_f32_16x16x32_bf16(a_q[0][0], k0, s0[0][nt], 0, 0, 0);
            s0[1][nt] = __builtin_amdgcn_mfma_f32_16x16x32_bf16(a_q[1][0], k0, s0[1][nt], 0, 0, 0);
            s0[0][nt] = __builtin_amdgcn_mfma_f32_16x16x32_bf16(a_q[0][1], k1, s0[0][nt], 0, 0, 0);
            s0[1][nt] = __builtin_amdgcn_mfma_f32_16x16x32_bf16(a_q[1][1], k1, s0[1][nt], 0, 0, 0);
        }

        // ---- static-max softmax: p = exp2(s*kscale - SMAX), lane-local lsum ----
        const bool diag = (jb == qi);
        #pragma unroll
        for (int s = 0; s < 2; ++s)
            #pragma unroll
            for (int nt = 0; nt < 4; ++nt)
                #pragma unroll
                for (int r = 0; r < 4; ++r) {
                    float raw = s0[s][nt][r];
                    if (diag) {
                        int n = nt * 16 + l16;
                        int m = half * 32 + s * 16 + quad * 4 + r;
                        if (n > m) raw = -INFINITY;
                    }
                    float p = exp2f(fmaf(raw, kscale, -SMAX));
                    s0[s][nt][r] = p;
                    lsum[s][r] += p;
                }

        // ---- P: C layout -> LDS -> A layout (wave-private, no barrier) ----
        #pragma unroll
        for (int s = 0; s < 2; ++s)
            #pragma unroll
            for (int nt = 0; nt < 4; ++nt)
                #pragma unroll
                for (int r = 0; r < 4; ++r)
                    pl[(s * 16 + quad * 4 + r) * KP + nt * 16 + l16] = f2bf(s0[s][nt][r]);
        bf16x8 a_p[2][2];
        #pragma unroll
        for (int s = 0; s < 2; ++s)
            #pragma unroll
            for (int kk = 0; kk < 2; ++kk)
                a_p[s][kk] = *(const bf16x8*)&pl[(s * 16 + l16) * KP + kk * 32 + quad * 8];

        // ---- O += P V : V^T B-frags direct from global bf16 [h][d][t] ----
        #pragma unroll
        for (int nt = 0; nt < 4; ++nt) {
            const short* vrow = vb + (size_t)(nt * 16 + l16) * SEQLEN + jb * 64 + quad * 8;
            bf16x8 v0 = *(const bf16x8*)(vrow);
            bf16x8 v1 = *(const bf16x8*)(vrow + 32);
            o[0][nt] = __builtin_amdgcn_mfma_f32_16x16x32_bf16(a_p[0][0], v0, o[0][nt], 0, 0, 0);
            o[1][nt] = __builtin_amdgcn_mfma_f32_16x16x32_bf16(a_p[1][0], v0, o[1][nt], 0, 0, 0);
            o[0][nt] = __builtin_amdgcn_mfma_f32_16x16x32_bf16(a_p[0][1], v1, o[0][nt], 0, 0, 0);
            o[1][nt] = __builtin_amdgcn_mfma_f32_16x16x32_bf16(a_p[1][1], v1, o[1][nt], 0, 0, 0);
        }
    }

    // ---- final l reduction (once) + epilogue ----
    #pragma unroll
    for (int s = 0; s < 2; ++s)
        #pragma unroll
        for (int r = 0; r < 4; ++r) {
            float t = lsum[s][r];
            #pragma unroll
            for (int off = 1; off < 16; off <<= 1)
                t += __shfl_xor(t, off);
            float inv = 1.0f / t;
            int trow = row0 + s * 16 + quad * 4 + r;
            float* orow = out + ((size_t)trow * NHEADS + h) * HDIM;
            #pragma unroll
            for (int nt = 0; nt < 4; ++nt)
                orow[nt * 16 + l16] = o[s][nt][r] * inv;
        }
}

// ---------------- fallback (round-1 kernel) if ws too small -----------------
__global__ __launch_bounds__(256)
void bs_attn_fallback(const float* __restrict__ q, const float* __restrict__ kg,
                      const float* __restrict__ vg, float* __restrict__ out) {
    __shared__ short kl[BSZ * KP];
    __shared__ short vt[HDIM * KP];
    __shared__ short pl[BSZ * KP];
    const int h = blockIdx.x & (NHEADS - 1);
    const int qi = blockIdx.x >> 4;
    const int tid = threadIdx.x;
    const int wave = tid >> 6, lane = tid & 63, l16 = lane & 15, quad = lane >> 4;
    const int mrow = qi * BSZ + wave * 16 + l16;
    const float* qrow = q + ((size_t)(mrow * NHEADS + h)) * HDIM;
    bf16x8 a_q[2];
    #pragma unroll
    for (int kk = 0; kk < 2; ++kk) {
        const float* src = qrow + kk * 32 + quad * 8;
        float4 f0 = *(const float4*)(src);
        float4 f1 = *(const float4*)(src + 4);
        bf16x8 a;
        a[0]=f2bf(f0.x); a[1]=f2bf(f0.y); a[2]=f2bf(f0.z); a[3]=f2bf(f0.w);
        a[4]=f2bf(f1.x); a[5]=f2bf(f1.y); a[6]=f2bf(f1.z); a[7]=f2bf(f1.w);
        a_q[kk] = a;
    }
    f32x4 o_acc[4];
    #pragma unroll
    for (int i = 0; i < 4; ++i) o_acc[i] = (f32x4){0.f, 0.f, 0.f, 0.f};
    float lsum[4];
    #pragma unroll
    for (int r = 0; r < 4; ++r) lsum[r] = 0.f;
    const float kscale = 0.125f * 1.4426950408889634f;
    for (int jb = 0; jb <= qi; ++jb) {
        if (!(((qi - jb) < 8) || (((jb + h + 1) & 7) == 0))) continue;
        __syncthreads();
        {
            int rg = tid >> 4, cg = (tid & 15) * 4;
            #pragma unroll
            for (int it = 0; it < 4; ++it) {
                int r = it * 16 + rg;
                const float* src = kg + ((size_t)((jb * BSZ + r) * NHEADS + h)) * HDIM + cg;
                float4 f = *(const float4*)src;
                short4 bq;
                bq.x = f2bf(f.x); bq.y = f2bf(f.y); bq.z = f2bf(f.z); bq.w = f2bf(f.w);
                *(short4*)&kl[r * KP + cg] = bq;
            }
        }
        {
            int key = tid & 63, c0 = (tid >> 6) * 16;
            const float* src = vg + ((size_t)((jb * BSZ + key) * NHEADS + h)) * HDIM + c0;
            #pragma unroll
            for (int j0 = 0; j0 < 16; j0 += 4) {
                float4 f = *(const float4*)(src + j0);
                vt[(c0 + j0 + 0) * KP + key] = f2bf(f.x);
                vt[(c0 + j0 + 1) * KP + key] = f2bf(f.y);
                vt[(c0 + j0 + 2) * KP + key] = f2bf(f.z);
                vt[(c0 + j0 + 3) * KP + key] = f2bf(f.w);
            }
        }
        __syncthreads();
        f32x4 s[4];
        #pragma unroll
        for (int nt = 0; nt < 4; ++nt) s[nt] = (f32x4){0.f, 0.f, 0.f, 0.f};
        #pragma unroll
        for (int nt = 0; nt < 4; ++nt)
            #pragma unroll
            for (int kk = 0; kk < 2; ++kk) {
                bf16x8 bfr = *(const bf16x8*)&kl[(nt * 16 + l16) * KP + kk * 32 + quad * 8];
                s[nt] = __builtin_amdgcn_mfma_f32_16x16x32_bf16(a_q[kk], bfr, s[nt], 0, 0, 0);
            }
        const bool diag = (jb == qi);
        #pragma unroll
        for (int nt = 0; nt < 4; ++nt)
            #pragma unroll
            for (int r = 0; r < 4; ++r) {
                float raw = s[nt][r];
                if (diag) {
                    int n = nt * 16 + l16, m = wave * 16 + quad * 4 + r;
                    if (n > m) raw = -INFINITY;
                }
                float p = exp2f(fmaf(raw, kscale, -SMAX));
                s[nt][r] = p;
                lsum[r] += p;
            }
        #pragma unroll
        for (int nt = 0; nt < 4; ++nt)
            #pragma unroll
            for (int r = 0; r < 4; ++r)
                pl[(wave * 16 + quad * 4 + r) * KP + nt * 16 + l16] = f2bf(s[nt][r]);
        bf16x8 a_p[2];
        #pragma unroll
        for (int kk = 0; kk < 2; ++kk)
            a_p[kk] = *(const bf16x8*)&pl[(wave * 16 + l16) * KP + kk * 32 + quad * 8];
        #pragma unroll
        for (int nt = 0; nt < 4; ++nt)
            #pragma unroll
            for (int kk = 0; kk < 2; ++kk) {
                bf16x8 bfr = *(const bf16x8*)&vt[(nt * 16 + l16) * KP + kk * 32 + quad * 8];
                o_acc[nt] = __builtin_amdgcn_mfma_f32_16x16x32_bf16(a_p[kk], bfr, o_acc[nt], 0, 0, 0);
            }
    }
    #pragma unroll
    for (int r = 0; r < 4; ++r) {
        float t = lsum[r];
        #pragma unroll
        for (int off = 1; off < 16; off <<= 1) t += __shfl_xor(t, off);
        float inv = 1.0f / t;
        int trow = qi * BSZ + wave * 16 + quad * 4 + r;
        float* orow = out + ((size_t)(trow * NHEADS + h)) * HDIM;
        #pragma unroll
        for (int nt = 0; nt < 4; ++nt)
            orow[nt * 16 + l16] = o_acc[nt][r] * inv;
    }
}

extern "C" void kernel_launch(void* const* d_in, const int* in_sizes, int n_in,
                              void* d_out, int out_size, void* d_ws, size_t ws_size,
                              hipStream_t stream) {
    const float* q = (const float*)d_in[0];
    const float* k = (const float*)d_in[1];
    const float* v = (const float*)d_in[2];
    float* out = (float*)d_out;

    const size_t khBytes = (size_t)NHEADS * SEQLEN * HDIM * sizeof(short); // 8 MiB
    if (ws_size >= 2 * khBytes) {
        short* kh  = (short*)d_ws;
        short* vth = (short*)((char*)d_ws + khBytes);
        prep_kernel<<<dim3(2 * NHEADS * NBLK), dim3(256), 0, stream>>>(k, v, kh, vth);
        attn_kernel<<<dim3(NHEADS * NBLK * 2), dim3(64), 0, stream>>>(kh, vth, q, out);
    } else {
        bs_attn_fallback<<<dim3(NHEADS * NBLK), dim3(256), 0, stream>>>(q, k, v, out);
    }
}